// Round 1
// baseline (117.968 us; speedup 1.0000x reference)
//
#include <hip/hip_runtime.h>

#define B_  2
#define V_  4
#define VS_ 3   // source views
#define C_  32
#define G_  8
#define D_  32
#define H_  128
#define W_  160

// ---------------------------------------------------------------------------
// 4x4 inverse (Gauss-Jordan with partial pivoting)
// ---------------------------------------------------------------------------
__device__ void inv4x4(const float* m, float* out) {
    float a[4][8];
    for (int i = 0; i < 4; i++) {
        for (int j = 0; j < 4; j++) {
            a[i][j]     = m[i * 4 + j];
            a[i][j + 4] = (i == j) ? 1.f : 0.f;
        }
    }
    for (int c = 0; c < 4; c++) {
        int piv = c;
        float best = fabsf(a[c][c]);
        for (int r = c + 1; r < 4; r++) {
            float v = fabsf(a[r][c]);
            if (v > best) { best = v; piv = r; }
        }
        if (piv != c) {
            for (int j = 0; j < 8; j++) {
                float t = a[c][j]; a[c][j] = a[piv][j]; a[piv][j] = t;
            }
        }
        float pv = 1.f / a[c][c];
        for (int j = 0; j < 8; j++) a[c][j] *= pv;
        for (int r = 0; r < 4; r++) {
            if (r == c) continue;
            float f = a[r][c];
            for (int j = 0; j < 8; j++) a[r][j] -= f * a[c][j];
        }
    }
    for (int i = 0; i < 4; i++)
        for (int j = 0; j < 4; j++) out[i * 4 + j] = a[i][j + 4];
}

// make_proj: ext = p[0], K = p[1]; result = ext with rows 0..2 = K[:3,:3] @ ext[:3,:4]
__device__ void make_proj(const float* p, float* o) {
    const float* ext = p;
    const float* K   = p + 16;
    for (int i = 0; i < 16; i++) o[i] = ext[i];
    for (int i = 0; i < 3; i++) {
        for (int j = 0; j < 4; j++) {
            float s = 0.f;
            for (int k = 0; k < 3; k++) s += K[i * 4 + k] * ext[k * 4 + j];
            o[i * 4 + j] = s;
        }
    }
}

// Per (b, src view): store rot(9) + trans(3) of src_proj @ inv(ref_proj)
__global__ void setup_proj_kernel(const float* __restrict__ proj,
                                  float* __restrict__ projp) {
    int t = threadIdx.x;
    if (t >= B_ * VS_) return;
    int b = t / VS_;
    int v = t % VS_ + 1;

    float refm[16], srcm[16], invr[16], P[16];
    make_proj(proj + ((size_t)(b * V_ + 0) * 2) * 16, refm);
    make_proj(proj + ((size_t)(b * V_ + v) * 2) * 16, srcm);
    inv4x4(refm, invr);
    for (int i = 0; i < 4; i++) {
        for (int j = 0; j < 4; j++) {
            float s = 0.f;
            for (int k = 0; k < 4; k++) s += srcm[i * 4 + k] * invr[k * 4 + j];
            P[i * 4 + j] = s;
        }
    }
    float* o = projp + t * 12;
    o[0] = P[0];  o[1] = P[1];  o[2]  = P[2];
    o[3] = P[4];  o[4] = P[5];  o[5]  = P[6];
    o[6] = P[8];  o[7] = P[9];  o[8]  = P[10];
    o[9] = P[3];  o[10] = P[7]; o[11] = P[11];
}

// ---------------------------------------------------------------------------
// (N, C, H, W) -> (N, H, W, C) channels-last transpose, one block per (n, y) row
// ---------------------------------------------------------------------------
__global__ __launch_bounds__(256) void transpose_kernel(const float* __restrict__ in,
                                                        float* __restrict__ out) {
    __shared__ float tile[C_][W_ + 1];
    int n = blockIdx.x / H_;
    int y = blockIdx.x % H_;
    for (int idx = threadIdx.x; idx < C_ * W_; idx += 256) {
        int c = idx / W_;
        int x = idx - c * W_;
        tile[c][x] = in[(((size_t)n * C_ + c) * H_ + y) * W_ + x];
    }
    __syncthreads();
    float* op = out + ((size_t)n * H_ + y) * W_ * C_;
    for (int idx = threadIdx.x; idx < W_ * C_; idx += 256) {
        int c = idx & (C_ - 1);
        int x = idx >> 5;
        op[idx] = tile[c][x];
    }
}

// ---------------------------------------------------------------------------
// Fused warp + group-correlation + view softmax + final softmax/argmax.
// One thread per (b, h, w, d); block = 8 pixels x 32 depths.
// ---------------------------------------------------------------------------
__global__ __launch_bounds__(256) void fused_kernel(const float* __restrict__ refT,
                                                    const float* __restrict__ srcT,
                                                    const float* __restrict__ projp,
                                                    const float* __restrict__ depth_hypo,
                                                    const float* __restrict__ reg_w,
                                                    float* __restrict__ out) {
    const int WT = W_ / 8;
    int bid = blockIdx.x;
    int b   = bid / (H_ * WT);
    int rem = bid % (H_ * WT);
    int h   = rem / WT;
    int w0  = (rem % WT) * 8;

    int tid = threadIdx.x;
    int d   = tid & 31;
    int p   = tid >> 5;
    int w   = w0 + p;

    // reference feature vector (32 ch) in registers; each float4 = one group
    float4 rf[8];
    const float4* rptr = (const float4*)(refT + (((size_t)b * H_ + h) * W_ + w) * C_);
#pragma unroll
    for (int k = 0; k < 8; k++) rf[k] = rptr[k];

    float depth = depth_hypo[(((size_t)b * D_ + d) * H_ + h) * W_ + w];

    float cf[8];
#pragma unroll
    for (int g = 0; g < 8; g++) cf[g] = 0.f;
    float cwsum = 1e-8f;

    float xf = (float)w, yf = (float)h;

    for (int v = 0; v < VS_; ++v) {
        const float* M = projp + (b * VS_ + v) * 12;
        float rx = M[0] * xf + M[1] * yf + M[2];
        float ry = M[3] * xf + M[4] * yf + M[5];
        float rz = M[6] * xf + M[7] * yf + M[8];
        float X = rx * depth + M[9];
        float Y = ry * depth + M[10];
        float Z = rz * depth + M[11];
        if (Z == 0.f) Z = 1e-9f;
        float ix = X / Z;
        float iy = Y / Z;
        float x0f = floorf(ix), y0f = floorf(iy);
        float wx1 = ix - x0f, wy1 = iy - y0f;
        float wx0 = 1.f - wx1, wy0 = 1.f - wy1;

        float gc[8];
#pragma unroll
        for (int g = 0; g < 8; g++) gc[g] = 0.f;

        const float* sbase = srcT + (size_t)(v * B_ + b) * H_ * W_ * C_;

        auto tap = [&](float xif, float yif, float wt) {
            if (xif >= 0.f && xif < (float)W_ && yif >= 0.f && yif < (float)H_) {
                int xi = (int)xif;
                int yi = (int)yif;
                const float4* sp = (const float4*)(sbase + ((size_t)yi * W_ + xi) * C_);
#pragma unroll
                for (int g = 0; g < 8; g++) {
                    float4 sv = sp[g];
                    gc[g] += wt * (rf[g].x * sv.x + rf[g].y * sv.y +
                                   rf[g].z * sv.z + rf[g].w * sv.w);
                }
            }
        };
        tap(x0f,       y0f,       wx0 * wy0);
        tap(x0f + 1.f, y0f,       wx1 * wy0);
        tap(x0f,       y0f + 1.f, wx0 * wy1);
        tap(x0f + 1.f, y0f + 1.f, wx1 * wy1);

        // cor[g] = mean over 4 channels; t = sum_g cor[g] / ATTN_TEMP
        float t = 0.f;
#pragma unroll
        for (int g = 0; g < 8; g++) { gc[g] *= 0.25f; t += gc[g]; }
        t *= 0.5f;  // / ATTN_TEMP (=2)

        // softmax over D (32 lanes of the half-wave)
        float m = t;
#pragma unroll
        for (int mask = 16; mask >= 1; mask >>= 1)
            m = fmaxf(m, __shfl_xor(m, mask));
        float e = __expf(t - m);
        float s = e;
#pragma unroll
        for (int mask = 16; mask >= 1; mask >>= 1)
            s += __shfl_xor(s, mask);
        float cw = e / s * 0.17677669529663689f;  // * 1/sqrt(C)

        cwsum += cw;
#pragma unroll
        for (int g = 0; g < 8; g++) cf[g] += cw * gc[g];
    }

    // logits = sum_g (cf[g]/cwsum) * reg_w[g]
    float logit = 0.f;
#pragma unroll
    for (int g = 0; g < 8; g++) logit += cf[g] * reg_w[g];
    logit /= cwsum;

    // final softmax over D
    float m = logit;
#pragma unroll
    for (int mask = 16; mask >= 1; mask >>= 1)
        m = fmaxf(m, __shfl_xor(m, mask));
    float e = __expf(logit - m);
    float s = e;
#pragma unroll
    for (int mask = 16; mask >= 1; mask >>= 1)
        s += __shfl_xor(s, mask);
    float attn = e / s;

    // argmax over D (first max wins, matching jnp.argmax)
    float bv = logit;
    int   bi = d;
#pragma unroll
    for (int mask = 16; mask >= 1; mask >>= 1) {
        float ov = __shfl_xor(bv, mask);
        int   oi = __shfl_xor(bi, mask);
        if (ov > bv || (ov == bv && oi < bi)) { bv = ov; bi = oi; }
    }

    if (d == 0) {
        float dep = depth_hypo[(((size_t)b * D_ + bi) * H_ + h) * W_ + w];
        out[((size_t)b * H_ + h) * W_ + w] = dep;
    }

    // attn store via LDS transpose for 32B-segment coalescing
    __shared__ float s_attn[8][33];
    s_attn[p][d] = attn;
    __syncthreads();
    int po = tid & 7;
    int d2 = tid >> 3;
    float* attn_out = out + (size_t)B_ * H_ * W_;
    attn_out[(((size_t)b * D_ + d2) * H_ + h) * W_ + w0 + po] = s_attn[po][d2];
}

// ---------------------------------------------------------------------------
extern "C" void kernel_launch(void* const* d_in, const int* in_sizes, int n_in,
                              void* d_out, int out_size, void* d_ws, size_t ws_size,
                              hipStream_t stream) {
    const float* ref_fea    = (const float*)d_in[0];
    const float* src_feas   = (const float*)d_in[1];
    const float* proj       = (const float*)d_in[2];
    const float* depth_hypo = (const float*)d_in[3];
    const float* reg_w      = (const float*)d_in[4];
    float* out = (float*)d_out;

    float* projp = (float*)d_ws;                       // 72 floats used
    float* refT  = projp + 256;                        // B*H*W*C
    float* srcT  = refT + (size_t)B_ * H_ * W_ * C_;   // VS*B*H*W*C

    setup_proj_kernel<<<1, 64, 0, stream>>>(proj, projp);
    transpose_kernel<<<B_ * H_, 256, 0, stream>>>(ref_fea, refT);
    transpose_kernel<<<VS_ * B_ * H_, 256, 0, stream>>>(src_feas, srcT);
    fused_kernel<<<B_ * H_ * (W_ / 8), 256, 0, stream>>>(refT, srcT, projp,
                                                         depth_hypo, reg_w, out);
}

// Round 3
// 114.351 us; speedup vs baseline: 1.0316x; 1.0316x over previous
//
#include <hip/hip_runtime.h>

#define B_  2
#define V_  4
#define VS_ 3   // source views
#define C_  32
#define G_  8
#define D_  32
#define H_  128
#define W_  160

// ---------------------------------------------------------------------------
// 4x4 inverse (Gauss-Jordan with partial pivoting)
// ---------------------------------------------------------------------------
__device__ void inv4x4(const float* m, float* out) {
    float a[4][8];
    for (int i = 0; i < 4; i++) {
        for (int j = 0; j < 4; j++) {
            a[i][j]     = m[i * 4 + j];
            a[i][j + 4] = (i == j) ? 1.f : 0.f;
        }
    }
    for (int c = 0; c < 4; c++) {
        int piv = c;
        float best = fabsf(a[c][c]);
        for (int r = c + 1; r < 4; r++) {
            float v = fabsf(a[r][c]);
            if (v > best) { best = v; piv = r; }
        }
        if (piv != c) {
            for (int j = 0; j < 8; j++) {
                float t = a[c][j]; a[c][j] = a[piv][j]; a[piv][j] = t;
            }
        }
        float pv = 1.f / a[c][c];
        for (int j = 0; j < 8; j++) a[c][j] *= pv;
        for (int r = 0; r < 4; r++) {
            if (r == c) continue;
            float f = a[r][c];
            for (int j = 0; j < 8; j++) a[r][j] -= f * a[c][j];
        }
    }
    for (int i = 0; i < 4; i++)
        for (int j = 0; j < 4; j++) out[i * 4 + j] = a[i][j + 4];
}

__device__ void make_proj(const float* p, float* o) {
    const float* ext = p;
    const float* K   = p + 16;
    for (int i = 0; i < 16; i++) o[i] = ext[i];
    for (int i = 0; i < 3; i++) {
        for (int j = 0; j < 4; j++) {
            float s = 0.f;
            for (int k = 0; k < 3; k++) s += K[i * 4 + k] * ext[k * 4 + j];
            o[i * 4 + j] = s;
        }
    }
}

// Per (b, src view): store rot(9) + trans(3) of src_proj @ inv(ref_proj)
__global__ void setup_proj_kernel(const float* __restrict__ proj,
                                  float* __restrict__ projp) {
    int t = threadIdx.x;
    if (t >= B_ * VS_) return;
    int b = t / VS_;
    int v = t % VS_ + 1;

    float refm[16], srcm[16], invr[16], P[16];
    make_proj(proj + ((size_t)(b * V_ + 0) * 2) * 16, refm);
    make_proj(proj + ((size_t)(b * V_ + v) * 2) * 16, srcm);
    inv4x4(refm, invr);
    for (int i = 0; i < 4; i++) {
        for (int j = 0; j < 4; j++) {
            float s = 0.f;
            for (int k = 0; k < 4; k++) s += srcm[i * 4 + k] * invr[k * 4 + j];
            P[i * 4 + j] = s;
        }
    }
    float* o = projp + t * 12;
    o[0] = P[0];  o[1] = P[1];  o[2]  = P[2];
    o[3] = P[4];  o[4] = P[5];  o[5]  = P[6];
    o[6] = P[8];  o[7] = P[9];  o[8]  = P[10];
    o[9] = P[3];  o[10] = P[7]; o[11] = P[11];
}

// ---------------------------------------------------------------------------
// (N, C, H, W) -> (N, H, W, C) channels-last transpose, one block per (n, y) row
// ---------------------------------------------------------------------------
__global__ __launch_bounds__(256) void transpose_kernel(const float* __restrict__ in,
                                                        float* __restrict__ out) {
    __shared__ float tile[C_][W_ + 1];
    int n = blockIdx.x / H_;
    int y = blockIdx.x % H_;
    for (int idx = threadIdx.x; idx < C_ * W_; idx += 256) {
        int c = idx / W_;
        int x = idx - c * W_;
        tile[c][x] = in[(((size_t)n * C_ + c) * H_ + y) * W_ + x];
    }
    __syncthreads();
    float* op = out + ((size_t)n * H_ + y) * W_ * C_;
    for (int idx = threadIdx.x; idx < W_ * C_; idx += 256) {
        int c = idx & (C_ - 1);
        int x = idx >> 5;
        op[idx] = tile[c][x];
    }
}

// ---------------------------------------------------------------------------
// Fused warp + group-correlation + view softmax + final softmax/argmax.
// One thread per (b, h, w, d); block = 8 pixels x 32 depths.
// Branchless taps; all 3 views' gathers issued before any softmax.
// ---------------------------------------------------------------------------
__global__ __launch_bounds__(256, 4) void fused_kernel(const float* __restrict__ ref_fea,
                                                       const float* __restrict__ srcT,
                                                       const float* __restrict__ projp,
                                                       const float* __restrict__ depth_hypo,
                                                       const float* __restrict__ reg_w,
                                                       float* __restrict__ out) {
    const int WT = W_ / 8;
    int bid = blockIdx.x;
    int b   = bid / (H_ * WT);
    int rem = bid % (H_ * WT);
    int h   = rem / WT;
    int w0  = (rem % WT) * 8;

    int tid = threadIdx.x;
    int d   = tid & 31;
    int p   = tid >> 5;
    int w   = w0 + p;

    // stage the 8 pixels' ref vectors into LDS (native layout, 1 float/thread)
    __shared__ float s_ref[8][32];
    {
        int c  = tid >> 3;
        int px = tid & 7;
        s_ref[px][c] = ref_fea[(((size_t)b * C_ + c) * H_ + h) * W_ + w0 + px];
    }
    __syncthreads();

    float depth = depth_hypo[(((size_t)b * D_ + d) * H_ + h) * W_ + w];

    float xf = (float)w, yf = (float)h;

    // ---- all 12 tap offsets + weights, branchless ----
    int   offs[VS_][4];
    float wts[VS_][4];
#pragma unroll
    for (int v = 0; v < VS_; ++v) {
        const float* M = projp + (b * VS_ + v) * 12;
        float rx = M[0] * xf + M[1] * yf + M[2];
        float ry = M[3] * xf + M[4] * yf + M[5];
        float rz = M[6] * xf + M[7] * yf + M[8];
        float X = rx * depth + M[9];
        float Y = ry * depth + M[10];
        float Z = rz * depth + M[11];
        if (Z == 0.f) Z = 1e-9f;
        float ix = X / Z;
        float iy = Y / Z;
        float x0f = floorf(ix), y0f = floorf(iy);
        float wx1 = ix - x0f, wy1 = iy - y0f;
        float wx0 = 1.f - wx1, wy0 = 1.f - wy1;

        int x0 = (int)x0f, y0 = (int)y0f;
        int xc0 = min(max(x0, 0), W_ - 1);
        int xc1 = min(max(x0 + 1, 0), W_ - 1);
        int yc0 = min(max(y0, 0), H_ - 1);
        int yc1 = min(max(y0 + 1, 0), H_ - 1);

        float vx0 = (x0f >= 0.f  && x0f <= (float)(W_ - 1)) ? 1.f : 0.f;
        float vx1 = (x0f >= -1.f && x0f <= (float)(W_ - 2)) ? 1.f : 0.f;
        float vy0 = (y0f >= 0.f  && y0f <= (float)(H_ - 1)) ? 1.f : 0.f;
        float vy1 = (y0f >= -1.f && y0f <= (float)(H_ - 2)) ? 1.f : 0.f;

        float ax0 = wx0 * vx0, ax1 = wx1 * vx1;
        float ay0 = wy0 * vy0, ay1 = wy1 * vy1;
        wts[v][0] = ax0 * ay0;
        wts[v][1] = ax1 * ay0;
        wts[v][2] = ax0 * ay1;
        wts[v][3] = ax1 * ay1;

        int r0 = yc0 * W_, r1 = yc1 * W_;
        offs[v][0] = (r0 + xc0) * (C_ / 4);
        offs[v][1] = (r0 + xc1) * (C_ / 4);
        offs[v][2] = (r1 + xc0) * (C_ / 4);
        offs[v][3] = (r1 + xc1) * (C_ / 4);
    }

    // ---- all gathers + correlations, no intervening cross-lane ops ----
    float gcv[VS_][G_];
#pragma unroll
    for (int v = 0; v < VS_; ++v) {
        const float4* sp = (const float4*)(srcT + (size_t)(v * B_ + b) * H_ * W_ * C_);
        float w00 = wts[v][0], w10 = wts[v][1], w01 = wts[v][2], w11 = wts[v][3];
        int o00 = offs[v][0], o10 = offs[v][1], o01 = offs[v][2], o11 = offs[v][3];
#pragma unroll
        for (int g = 0; g < G_; ++g) {
            float4 t00 = sp[o00 + g];
            float4 t10 = sp[o10 + g];
            float4 t01 = sp[o01 + g];
            float4 t11 = sp[o11 + g];
            float wsx = w00 * t00.x + w10 * t10.x + w01 * t01.x + w11 * t11.x;
            float wsy = w00 * t00.y + w10 * t10.y + w01 * t01.y + w11 * t11.y;
            float wsz = w00 * t00.z + w10 * t10.z + w01 * t01.z + w11 * t11.z;
            float wsw = w00 * t00.w + w10 * t10.w + w01 * t01.w + w11 * t11.w;
            float4 r = *(const float4*)&s_ref[p][g * 4];
            gcv[v][g] = 0.25f * (r.x * wsx + r.y * wsy + r.z * wsz + r.w * wsw);
        }
    }

    // ---- per-view softmax over D + weighted accumulation ----
    float cf[G_];
#pragma unroll
    for (int g = 0; g < G_; g++) cf[g] = 0.f;
    float cwsum = 1e-8f;

#pragma unroll
    for (int v = 0; v < VS_; ++v) {
        float t = 0.f;
#pragma unroll
        for (int g = 0; g < G_; g++) t += gcv[v][g];
        t *= 0.5f;  // / ATTN_TEMP

        float m = t;
#pragma unroll
        for (int mask = 16; mask >= 1; mask >>= 1)
            m = fmaxf(m, __shfl_xor(m, mask));
        float e = __expf(t - m);
        float s = e;
#pragma unroll
        for (int mask = 16; mask >= 1; mask >>= 1)
            s += __shfl_xor(s, mask);
        float cw = e / s * 0.17677669529663689f;  // * 1/sqrt(C)

        cwsum += cw;
#pragma unroll
        for (int g = 0; g < G_; g++) cf[g] += cw * gcv[v][g];
    }

    // logits = sum_g (cf[g]/cwsum) * reg_w[g]
    float logit = 0.f;
#pragma unroll
    for (int g = 0; g < G_; g++) logit += cf[g] * reg_w[g];
    logit /= cwsum;

    // final softmax over D
    float m = logit;
#pragma unroll
    for (int mask = 16; mask >= 1; mask >>= 1)
        m = fmaxf(m, __shfl_xor(m, mask));
    float e = __expf(logit - m);
    float s = e;
#pragma unroll
    for (int mask = 16; mask >= 1; mask >>= 1)
        s += __shfl_xor(s, mask);
    float attn = e / s;

    // argmax over D (first max wins, matching jnp.argmax)
    float bv = logit;
    int   bi = d;
#pragma unroll
    for (int mask = 16; mask >= 1; mask >>= 1) {
        float ov = __shfl_xor(bv, mask);
        int   oi = __shfl_xor(bi, mask);
        if (ov > bv || (ov == bv && oi < bi)) { bv = ov; bi = oi; }
    }

    // shuffle MUST happen with all lanes active (ds_bpermute reads from
    // exec-masked-off lanes return 0 on CDNA) — hoist above the branch.
    float dep = __shfl(depth, bi, 32);
    if (d == 0) {
        out[((size_t)b * H_ + h) * W_ + w] = dep;
    }

    // attn store via LDS transpose for 32B-segment coalescing
    __shared__ float s_attn[8][33];
    s_attn[p][d] = attn;
    __syncthreads();
    int po = tid & 7;
    int d2 = tid >> 3;
    float* attn_out = out + (size_t)B_ * H_ * W_;
    attn_out[(((size_t)b * D_ + d2) * H_ + h) * W_ + w0 + po] = s_attn[po][d2];
}

// ---------------------------------------------------------------------------
extern "C" void kernel_launch(void* const* d_in, const int* in_sizes, int n_in,
                              void* d_out, int out_size, void* d_ws, size_t ws_size,
                              hipStream_t stream) {
    const float* ref_fea    = (const float*)d_in[0];
    const float* src_feas   = (const float*)d_in[1];
    const float* proj       = (const float*)d_in[2];
    const float* depth_hypo = (const float*)d_in[3];
    const float* reg_w      = (const float*)d_in[4];
    float* out = (float*)d_out;

    float* projp = (float*)d_ws;                       // 72 floats used
    float* srcT  = projp + 256;                        // VS*B*H*W*C

    setup_proj_kernel<<<1, 64, 0, stream>>>(proj, projp);
    transpose_kernel<<<VS_ * B_ * H_, 256, 0, stream>>>(src_feas, srcT);
    fused_kernel<<<B_ * H_ * (W_ / 8), 256, 0, stream>>>(ref_fea, srcT, projp,
                                                         depth_hypo, reg_w, out);
}

// Round 4
// 110.615 us; speedup vs baseline: 1.0665x; 1.0338x over previous
//
#include <hip/hip_runtime.h>

#define B_  2
#define V_  4
#define VS_ 3   // source views
#define C_  32
#define G_  8
#define D_  32
#define H_  128
#define W_  160

// ---------------------------------------------------------------------------
// 4x4 inverse (Gauss-Jordan with partial pivoting)
// ---------------------------------------------------------------------------
__device__ void inv4x4(const float* m, float* out) {
    float a[4][8];
    for (int i = 0; i < 4; i++) {
        for (int j = 0; j < 4; j++) {
            a[i][j]     = m[i * 4 + j];
            a[i][j + 4] = (i == j) ? 1.f : 0.f;
        }
    }
    for (int c = 0; c < 4; c++) {
        int piv = c;
        float best = fabsf(a[c][c]);
        for (int r = c + 1; r < 4; r++) {
            float v = fabsf(a[r][c]);
            if (v > best) { best = v; piv = r; }
        }
        if (piv != c) {
            for (int j = 0; j < 8; j++) {
                float t = a[c][j]; a[c][j] = a[piv][j]; a[piv][j] = t;
            }
        }
        float pv = 1.f / a[c][c];
        for (int j = 0; j < 8; j++) a[c][j] *= pv;
        for (int r = 0; r < 4; r++) {
            if (r == c) continue;
            float f = a[r][c];
            for (int j = 0; j < 8; j++) a[r][j] -= f * a[c][j];
        }
    }
    for (int i = 0; i < 4; i++)
        for (int j = 0; j < 4; j++) out[i * 4 + j] = a[i][j + 4];
}

__device__ void make_proj(const float* p, float* o) {
    const float* ext = p;
    const float* K   = p + 16;
    for (int i = 0; i < 16; i++) o[i] = ext[i];
    for (int i = 0; i < 3; i++) {
        for (int j = 0; j < 4; j++) {
            float s = 0.f;
            for (int k = 0; k < 3; k++) s += K[i * 4 + k] * ext[k * 4 + j];
            o[i * 4 + j] = s;
        }
    }
}

// Per (b, src view): store rot(9) + trans(3) of src_proj @ inv(ref_proj)
__global__ void setup_proj_kernel(const float* __restrict__ proj,
                                  float* __restrict__ projp) {
    int t = threadIdx.x;
    if (t >= B_ * VS_) return;
    int b = t / VS_;
    int v = t % VS_ + 1;

    float refm[16], srcm[16], invr[16], P[16];
    make_proj(proj + ((size_t)(b * V_ + 0) * 2) * 16, refm);
    make_proj(proj + ((size_t)(b * V_ + v) * 2) * 16, srcm);
    inv4x4(refm, invr);
    for (int i = 0; i < 4; i++) {
        for (int j = 0; j < 4; j++) {
            float s = 0.f;
            for (int k = 0; k < 4; k++) s += srcm[i * 4 + k] * invr[k * 4 + j];
            P[i * 4 + j] = s;
        }
    }
    float* o = projp + t * 12;
    o[0] = P[0];  o[1] = P[1];  o[2]  = P[2];
    o[3] = P[4];  o[4] = P[5];  o[5]  = P[6];
    o[6] = P[8];  o[7] = P[9];  o[8]  = P[10];
    o[9] = P[3];  o[10] = P[7]; o[11] = P[11];
}

// ---------------------------------------------------------------------------
// (N, C, H, W) -> (N, H, W, C) channels-last transpose, one block per (n, y) row
// ---------------------------------------------------------------------------
__global__ __launch_bounds__(256) void transpose_kernel(const float* __restrict__ in,
                                                        float* __restrict__ out) {
    __shared__ float tile[C_][W_ + 1];
    int n = blockIdx.x / H_;
    int y = blockIdx.x % H_;
    for (int idx = threadIdx.x; idx < C_ * W_; idx += 256) {
        int c = idx / W_;
        int x = idx - c * W_;
        tile[c][x] = in[(((size_t)n * C_ + c) * H_ + y) * W_ + x];
    }
    __syncthreads();
    float* op = out + ((size_t)n * H_ + y) * W_ * C_;
    for (int idx = threadIdx.x; idx < W_ * C_; idx += 256) {
        int c = idx & (C_ - 1);
        int x = idx >> 5;
        op[idx] = tile[c][x];
    }
}

// ---------------------------------------------------------------------------
// Fused warp + group-correlation + view softmax + final softmax/argmax.
// One thread per (b, h, w, d); block = 8 pixels x 32 depths.
// Per-view state reduced to TWO scalars (S = ref·warped, R = (ref⊙reg_w)·warped)
// so all 96 gather loads can be in flight without spills.
// ---------------------------------------------------------------------------
__global__ __launch_bounds__(256) void fused_kernel(const float* __restrict__ ref_fea,
                                                    const float* __restrict__ srcT,
                                                    const float* __restrict__ projp,
                                                    const float* __restrict__ depth_hypo,
                                                    const float* __restrict__ reg_w,
                                                    float* __restrict__ out) {
    const int WT = W_ / 8;
    int bid = blockIdx.x;
    int b   = bid / (H_ * WT);
    int rem = bid % (H_ * WT);
    int h   = rem / WT;
    int w0  = (rem % WT) * 8;

    int tid = threadIdx.x;
    int d   = tid & 31;
    int p   = tid >> 5;
    int w   = w0 + p;

    // stage the 8 pixels' ref vectors (and reg_w-weighted copy) into LDS
    __shared__ float s_ref[8][32];
    __shared__ float s_rw[8][32];
    {
        int c  = tid >> 3;
        int px = tid & 7;
        float val = ref_fea[(((size_t)b * C_ + c) * H_ + h) * W_ + w0 + px];
        s_ref[px][c] = val;
        s_rw[px][c]  = val * reg_w[c >> 2];
    }
    __syncthreads();

    float depth = depth_hypo[(((size_t)b * D_ + d) * H_ + h) * W_ + w];

    float xf = (float)w, yf = (float)h;

    // ---- all 12 tap offsets + weights, branchless ----
    int   offs[VS_][4];
    float wts[VS_][4];
#pragma unroll
    for (int v = 0; v < VS_; ++v) {
        const float* M = projp + (b * VS_ + v) * 12;
        float rx = M[0] * xf + M[1] * yf + M[2];
        float ry = M[3] * xf + M[4] * yf + M[5];
        float rz = M[6] * xf + M[7] * yf + M[8];
        float X = rx * depth + M[9];
        float Y = ry * depth + M[10];
        float Z = rz * depth + M[11];
        if (Z == 0.f) Z = 1e-9f;
        float ix = X / Z;
        float iy = Y / Z;
        float x0f = floorf(ix), y0f = floorf(iy);
        float wx1 = ix - x0f, wy1 = iy - y0f;
        float wx0 = 1.f - wx1, wy0 = 1.f - wy1;

        int x0 = (int)x0f, y0 = (int)y0f;
        int xc0 = min(max(x0, 0), W_ - 1);
        int xc1 = min(max(x0 + 1, 0), W_ - 1);
        int yc0 = min(max(y0, 0), H_ - 1);
        int yc1 = min(max(y0 + 1, 0), H_ - 1);

        float vx0 = (x0f >= 0.f  && x0f <= (float)(W_ - 1)) ? 1.f : 0.f;
        float vx1 = (x0f >= -1.f && x0f <= (float)(W_ - 2)) ? 1.f : 0.f;
        float vy0 = (y0f >= 0.f  && y0f <= (float)(H_ - 1)) ? 1.f : 0.f;
        float vy1 = (y0f >= -1.f && y0f <= (float)(H_ - 2)) ? 1.f : 0.f;

        float ax0 = wx0 * vx0, ax1 = wx1 * vx1;
        float ay0 = wy0 * vy0, ay1 = wy1 * vy1;
        wts[v][0] = ax0 * ay0;
        wts[v][1] = ax1 * ay0;
        wts[v][2] = ax0 * ay1;
        wts[v][3] = ax1 * ay1;

        int r0 = yc0 * W_, r1 = yc1 * W_;
        offs[v][0] = (r0 + xc0) * (C_ / 4);
        offs[v][1] = (r0 + xc1) * (C_ / 4);
        offs[v][2] = (r1 + xc0) * (C_ / 4);
        offs[v][3] = (r1 + xc1) * (C_ / 4);
    }

    // ---- all gathers + two-scalar reduction per view, no cross-lane ops ----
    float Sv[VS_], Rv[VS_];
#pragma unroll
    for (int v = 0; v < VS_; ++v) {
        const float4* sp = (const float4*)(srcT + (size_t)(v * B_ + b) * H_ * W_ * C_);
        float w00 = wts[v][0], w10 = wts[v][1], w01 = wts[v][2], w11 = wts[v][3];
        int o00 = offs[v][0], o10 = offs[v][1], o01 = offs[v][2], o11 = offs[v][3];
        float sS = 0.f, sR = 0.f;
#pragma unroll
        for (int g = 0; g < G_; ++g) {
            float4 t00 = sp[o00 + g];
            float4 t10 = sp[o10 + g];
            float4 t01 = sp[o01 + g];
            float4 t11 = sp[o11 + g];
            float wsx = w00 * t00.x + w10 * t10.x + w01 * t01.x + w11 * t11.x;
            float wsy = w00 * t00.y + w10 * t10.y + w01 * t01.y + w11 * t11.y;
            float wsz = w00 * t00.z + w10 * t10.z + w01 * t01.z + w11 * t11.z;
            float wsw = w00 * t00.w + w10 * t10.w + w01 * t01.w + w11 * t11.w;
            float4 r  = *(const float4*)&s_ref[p][g * 4];
            float4 r2 = *(const float4*)&s_rw[p][g * 4];
            sS += r.x  * wsx + r.y  * wsy + r.z  * wsz + r.w  * wsw;
            sR += r2.x * wsx + r2.y * wsy + r2.z * wsz + r2.w * wsw;
        }
        Sv[v] = sS;
        Rv[v] = sR;
    }

    // ---- per-view softmax over D + scalar accumulation ----
    float cwsum = 1e-8f;
    float acc   = 0.f;
#pragma unroll
    for (int v = 0; v < VS_; ++v) {
        float t = Sv[v] * 0.125f;  // *0.25 (group mean) * 0.5 (1/ATTN_TEMP)

        float m = t;
#pragma unroll
        for (int mask = 16; mask >= 1; mask >>= 1)
            m = fmaxf(m, __shfl_xor(m, mask));
        float e = __expf(t - m);
        float s = e;
#pragma unroll
        for (int mask = 16; mask >= 1; mask >>= 1)
            s += __shfl_xor(s, mask);
        float cw = e / s * 0.17677669529663689f;  // * 1/sqrt(C)

        cwsum += cw;
        acc   += cw * (Rv[v] * 0.25f);
    }

    float logit = acc / cwsum;

    // final softmax over D
    float m = logit;
#pragma unroll
    for (int mask = 16; mask >= 1; mask >>= 1)
        m = fmaxf(m, __shfl_xor(m, mask));
    float e = __expf(logit - m);
    float s = e;
#pragma unroll
    for (int mask = 16; mask >= 1; mask >>= 1)
        s += __shfl_xor(s, mask);
    float attn = e / s;

    // argmax over D (first max wins, matching jnp.argmax)
    float bv = logit;
    int   bi = d;
#pragma unroll
    for (int mask = 16; mask >= 1; mask >>= 1) {
        float ov = __shfl_xor(bv, mask);
        int   oi = __shfl_xor(bi, mask);
        if (ov > bv || (ov == bv && oi < bi)) { bv = ov; bi = oi; }
    }

    // shuffle with all lanes active (exec-masked ds_bpermute returns 0)
    float dep = __shfl(depth, bi, 32);
    if (d == 0) {
        out[((size_t)b * H_ + h) * W_ + w] = dep;
    }

    // attn store via LDS transpose for 32B-segment coalescing
    __shared__ float s_attn[8][33];
    s_attn[p][d] = attn;
    __syncthreads();
    int po = tid & 7;
    int d2 = tid >> 3;
    float* attn_out = out + (size_t)B_ * H_ * W_;
    attn_out[(((size_t)b * D_ + d2) * H_ + h) * W_ + w0 + po] = s_attn[po][d2];
}

// ---------------------------------------------------------------------------
extern "C" void kernel_launch(void* const* d_in, const int* in_sizes, int n_in,
                              void* d_out, int out_size, void* d_ws, size_t ws_size,
                              hipStream_t stream) {
    const float* ref_fea    = (const float*)d_in[0];
    const float* src_feas   = (const float*)d_in[1];
    const float* proj       = (const float*)d_in[2];
    const float* depth_hypo = (const float*)d_in[3];
    const float* reg_w      = (const float*)d_in[4];
    float* out = (float*)d_out;

    float* projp = (float*)d_ws;                       // 72 floats used
    float* srcT  = projp + 256;                        // VS*B*H*W*C

    setup_proj_kernel<<<1, 64, 0, stream>>>(proj, projp);
    transpose_kernel<<<VS_ * B_ * H_, 256, 0, stream>>>(src_feas, srcT);
    fused_kernel<<<B_ * H_ * (W_ / 8), 256, 0, stream>>>(ref_fea, srcT, projp,
                                                         depth_hypo, reg_w, out);
}